// Round 5
// baseline (70.302 us; speedup 1.0000x reference)
//
#include <hip/hip_runtime.h>
#include <hip/hip_bf16.h>

// Fused stream-compaction: B=64, S=512, H=1024, fp32.
// One block per 8 consecutive OUTPUT rows of one batch row. The block
// rebuilds the 512-bit validity mask (2 KB of valid_ids, L2-resident),
// computes block-uniform source indices for its 8 rows with STATIC register
// indexing only, then copies/zero-fills 8 x 4 KB rows with coalesced,
// NONTEMPORAL float4 accesses (both streams are read-once/write-once).

typedef float v4f __attribute__((ext_vector_type(4)));

constexpr int ROWS = 8;   // output rows per block; S/ROWS = 64 chunks

__global__ __launch_bounds__(256) void compact_fused8(
    const v4f* __restrict__ in,         // [B*S*256] float4
    const int* __restrict__ valid,      // [B*S]
    v4f* __restrict__ out) {            // [B*S*256] float4
    const int bid = blockIdx.x;         // b * 64 + chunk
    const int b = bid >> 6;
    const int jbase = (bid & 63) * ROWS;
    const int t = threadIdx.x;          // 256 threads
    const int lane = t & 63;
    const int wave = t >> 6;            // 0..3

    // --- Build the 512-bit mask as 8 x u64 in LDS ---------------------------
    const int base = b << 9;            // b * 512
    const int v0 = (valid[base + t] == 1);
    const int v1 = (valid[base + t + 256] == 1);
    unsigned long long bal0 = __ballot(v0 != 0);   // positions [wave*64, +64)
    unsigned long long bal1 = __ballot(v1 != 0);   // positions [256+wave*64, +64)

    __shared__ unsigned long long words[8];
    if (lane == 0) {
        words[wave] = bal0;
        words[wave + 4] = bal1;
    }
    __syncthreads();

    // --- Block-uniform popcounts + prefix sums (all static indexing) --------
    const int c0 = __popcll(words[0]), c1 = __popcll(words[1]),
              c2 = __popcll(words[2]), c3 = __popcll(words[3]),
              c4 = __popcll(words[4]), c5 = __popcll(words[5]),
              c6 = __popcll(words[6]), c7 = __popcll(words[7]);
    const int p1 = c0,      p2 = p1 + c1, p3 = p2 + c2, p4 = p3 + c3,
              p5 = p4 + c4, p6 = p5 + c5, p7 = p6 + c6;
    const int nvalid = p7 + c7;

    // --- Precompute all 8 source indices (block-uniform, static indexing) ---
    int src[ROWS];                       // fully unrolled -> stays in VGPRs
    #pragma unroll
    for (int r = 0; r < ROWS; ++r) {
        const int j = jbase + r;
        int wsel = 0, psel = 0;
        if (j >= p1) { wsel = 1; psel = p1; }
        if (j >= p2) { wsel = 2; psel = p2; }
        if (j >= p3) { wsel = 3; psel = p3; }
        if (j >= p4) { wsel = 4; psel = p4; }
        if (j >= p5) { wsel = 5; psel = p5; }
        if (j >= p6) { wsel = 6; psel = p6; }
        if (j >= p7) { wsel = 7; psel = p7; }
        int k = j - psel;                       // 0-based rank in word
        unsigned long long x = words[wsel];     // LDS dyn index: fine

        // k-th set bit via 6-step popcount binary search (uniform).
        int pos = 0;
        #pragma unroll
        for (int hb = 5; hb >= 0; --hb) {
            const int half = 1 << hb;
            const unsigned long long m =
                (half == 32) ? 0xFFFFFFFFull : ((1ull << half) - 1ull);
            const int c = __popcll(x & m);
            if (k >= c) { k -= c; x >>= half; pos += half; }
        }
        src[r] = (j < nvalid) ? ((wsel << 6) + pos) : -1;
    }

    const v4f zero = {0.f, 0.f, 0.f, 0.f};

    // --- Issue all loads first (MLP), then all stores -----------------------
    v4f val[ROWS];
    #pragma unroll
    for (int r = 0; r < ROWS; ++r) {
        if (src[r] >= 0) {
            const long long irow = (long long)(base + src[r]) << 8;
            val[r] = __builtin_nontemporal_load(&in[irow + t]);
        } else {
            val[r] = zero;
        }
    }
    #pragma unroll
    for (int r = 0; r < ROWS; ++r) {
        const long long orow = (long long)(base + jbase + r) << 8;
        __builtin_nontemporal_store(val[r], &out[orow + t]);
    }
}

extern "C" void kernel_launch(void* const* d_in, const int* in_sizes, int n_in,
                              void* d_out, int out_size, void* d_ws, size_t ws_size,
                              hipStream_t stream) {
    const float* seq = (const float*)d_in[0];   // [B, S, H] fp32
    const int* valid = (const int*)d_in[1];     // [B, S] int32

    const int BS = in_sizes[1];                 // B * S = 32768
    const int nblocks = BS / ROWS;              // 4096

    compact_fused8<<<nblocks, 256, 0, stream>>>(
        (const v4f*)seq, valid, (v4f*)d_out);
}

// Round 6
// 34.246 us; speedup vs baseline: 2.0529x; 2.0529x over previous
//
#include <hip/hip_runtime.h>
#include <hip/hip_bf16.h>

// Fused stream-compaction: B=64, S=512, H=1024, fp32.  (R4 revert — best known)
// One block per 8 consecutive OUTPUT rows of one batch row. The block
// rebuilds the 512-bit validity mask (2 KB of valid_ids, L2-resident),
// computes block-uniform source indices for its 8 rows with STATIC register
// indexing only (no scratch demotion), then copies/zero-fills 8 x 4 KB rows
// with coalesced, CACHED float4 accesses (NT stores regress 2x on CDNA4:
// they defeat L2 write-combining — R5 evidence).

typedef float v4f __attribute__((ext_vector_type(4)));

constexpr int ROWS = 8;   // output rows per block; S/ROWS = 64 chunks

__global__ __launch_bounds__(256) void compact_fused8(
    const v4f* __restrict__ in,         // [B*S*256] float4
    const int* __restrict__ valid,      // [B*S]
    v4f* __restrict__ out) {            // [B*S*256] float4
    const int bid = blockIdx.x;         // b * 64 + chunk
    const int b = bid >> 6;
    const int jbase = (bid & 63) * ROWS;
    const int t = threadIdx.x;          // 256 threads
    const int lane = t & 63;
    const int wave = t >> 6;            // 0..3

    // --- Build the 512-bit mask as 8 x u64 in LDS ---------------------------
    const int base = b << 9;            // b * 512
    const int v0 = (valid[base + t] == 1);
    const int v1 = (valid[base + t + 256] == 1);
    unsigned long long bal0 = __ballot(v0 != 0);   // positions [wave*64, +64)
    unsigned long long bal1 = __ballot(v1 != 0);   // positions [256+wave*64, +64)

    __shared__ unsigned long long words[8];
    if (lane == 0) {
        words[wave] = bal0;
        words[wave + 4] = bal1;
    }
    __syncthreads();

    // --- Block-uniform popcounts + prefix sums (all static indexing) --------
    const int c0 = __popcll(words[0]), c1 = __popcll(words[1]),
              c2 = __popcll(words[2]), c3 = __popcll(words[3]),
              c4 = __popcll(words[4]), c5 = __popcll(words[5]),
              c6 = __popcll(words[6]), c7 = __popcll(words[7]);
    const int p1 = c0,      p2 = p1 + c1, p3 = p2 + c2, p4 = p3 + c3,
              p5 = p4 + c4, p6 = p5 + c5, p7 = p6 + c6;
    const int nvalid = p7 + c7;

    const v4f zero = {0.f, 0.f, 0.f, 0.f};

    #pragma unroll
    for (int r = 0; r < ROWS; ++r) {
        const int j = jbase + r;
        const long long orow = (long long)(base + j) << 8;   // *256 float4
        if (j < nvalid) {
            // Which 64-bit word holds the j-th set bit (static compare chain).
            int wsel = 0, psel = 0;
            if (j >= p1) { wsel = 1; psel = p1; }
            if (j >= p2) { wsel = 2; psel = p2; }
            if (j >= p3) { wsel = 3; psel = p3; }
            if (j >= p4) { wsel = 4; psel = p4; }
            if (j >= p5) { wsel = 5; psel = p5; }
            if (j >= p6) { wsel = 6; psel = p6; }
            if (j >= p7) { wsel = 7; psel = p7; }
            int k = j - psel;                       // 0-based rank in word
            unsigned long long x = words[wsel];     // LDS dyn index: fine

            // k-th set bit via 6-step popcount binary search (uniform).
            int pos = 0;
            #pragma unroll
            for (int hb = 5; hb >= 0; --hb) {
                const int half = 1 << hb;
                const unsigned long long m =
                    (half == 32) ? 0xFFFFFFFFull : ((1ull << half) - 1ull);
                const int c = __popcll(x & m);
                if (k >= c) { k -= c; x >>= half; pos += half; }
            }
            const int s = (wsel << 6) + pos;

            const long long irow = (long long)(base + s) << 8;
            out[orow + t] = in[irow + t];
        } else {
            out[orow + t] = zero;
        }
    }
}

extern "C" void kernel_launch(void* const* d_in, const int* in_sizes, int n_in,
                              void* d_out, int out_size, void* d_ws, size_t ws_size,
                              hipStream_t stream) {
    const float* seq = (const float*)d_in[0];   // [B, S, H] fp32
    const int* valid = (const int*)d_in[1];     // [B, S] int32

    const int BS = in_sizes[1];                 // B * S = 32768
    const int nblocks = BS / ROWS;              // 4096

    compact_fused8<<<nblocks, 256, 0, stream>>>(
        (const v4f*)seq, valid, (v4f*)d_out);
}